// Round 13
// baseline (188.856 us; speedup 1.0000x reference)
//
#include <hip/hip_runtime.h>

// Bidirectional GRU (H=32, input=1, B=2048, T=512) + MLP head, fully fused.
//
// Reference takes out[:, -1, :] = concat(h_fwd after T steps, h_bwd after ONE
// step from h0=0 on x[T-1]) -> only the forward scan is sequential; W_hh_b is
// entirely unused.
//
// R13 = R12 with dpp() as a template (mov_dpp ctrl must be a compile-time
// constant).  Design: replace the in-loop LDS h-broadcast with a register
// all-gather (DPP + ds_swizzle), removing the ~130-150 cyc LDS round-trip
// that sat on the per-step serial chain (R8/R11: 532 cyc/step = ~300 issue
// + ~210 exposed lgkm stall at 1 wave/SIMD).
//
// All-gather of 32 h (f16) across each 32-lane row group, all XOR stages:
//   xor1  : DPP quad_perm(1,0,3,2)      -> pack pairs (h2)
//   xor2  : DPP quad_perm(2,3,0,1)
//   xor4  : DPP row_half_mirror  (= xor7 on 3-bit lane field)
//   xor8  : DPP row_mirror       (= xor15)
//   xor16 : ds_swizzle 0x401F    (crossbar only: no memory, no barrier)
// The gathered slots arrive in a lane-dependent XOR order; instead of
// reordering (cndmasks), each lane loads its WEIGHTS pre-permuted to match:
// slot s of lane g uses cols g^e0(s), g^e1(s) with the fixed table
//   E = (0,1)(2,3)(7,6)(5,4)(15,14)(13,12)(8,9)(10,11)
//       (16,17)(18,19)(23,22)(21,20)(31,30)(29,28)(24,25)(26,27).
// Own-half dots (slots 0-7) issue while the 8 swizzles are in flight.
//
// Everything else from R11: 32 lanes/row, 2 rows/wave as half-waves, 1024
// waves = 1 wave/SIMD; f16 dot2 with f32 accumulate; weights pinned;
// exp2-domain gates; x staged in LDS as vf4 per 4 steps; same epilogue.

typedef float vf2 __attribute__((ext_vector_type(2)));
typedef float vf4 __attribute__((ext_vector_type(4)));
typedef _Float16 f16;
typedef f16 h2 __attribute__((ext_vector_type(2)));

#define TT 512
#define HH 32

#define PIN(v) asm volatile("" : "+v"(v))

#define LOG2E 1.44269504f

__device__ __forceinline__ float fast_sigm(float a) {
  return __builtin_amdgcn_rcpf(1.0f + __builtin_amdgcn_exp2f(-LOG2E * a));
}
__device__ __forceinline__ float fast_tanh(float a) {
  return __builtin_fmaf(-2.0f,
      __builtin_amdgcn_rcpf(1.0f + __builtin_amdgcn_exp2f(2.0f * LOG2E * a)),
      1.0f);
}

template <int CTRL>
__device__ __forceinline__ int dpp(int v) {
  return __builtin_amdgcn_mov_dpp(v, CTRL, 0xF, 0xF, true);
}
#define DPP_X1 0xB1   // quad_perm(1,0,3,2)
#define DPP_X2 0x4E   // quad_perm(2,3,0,1)
#define DPP_HM 0x141  // row_half_mirror (xor7)
#define DPP_M  0x140  // row_mirror (xor15)
#define SWZ_X16 0x401F

__device__ __forceinline__ h2 asH2(int v) { return __builtin_bit_cast(h2, v); }
__device__ __forceinline__ int asI(h2 v) { return __builtin_bit_cast(int, v); }

// weight pair for slot with xor-offsets e0,e1 (cols g^e0, g^e1), pre-scaled
__device__ __forceinline__ h2 wpair(const float* Wrow, int g, int e0, int e1,
                                    float s) {
  h2 r = {(f16)(Wrow[g ^ e0] * s), (f16)(Wrow[g ^ e1] * s)};
  return r;
}

// 16 weight slots for one gate row, matching the gather's slot order
#define LDWG(P, ROWPTR, S) \
  h2 P##0 = wpair(ROWPTR, g, 0, 1, S),   P##1 = wpair(ROWPTR, g, 2, 3, S), \
     P##2 = wpair(ROWPTR, g, 7, 6, S),   P##3 = wpair(ROWPTR, g, 5, 4, S), \
     P##4 = wpair(ROWPTR, g, 15, 14, S), P##5 = wpair(ROWPTR, g, 13, 12, S), \
     P##6 = wpair(ROWPTR, g, 8, 9, S),   P##7 = wpair(ROWPTR, g, 10, 11, S), \
     P##8 = wpair(ROWPTR, g, 16, 17, S), P##9 = wpair(ROWPTR, g, 18, 19, S), \
     P##A = wpair(ROWPTR, g, 23, 22, S), P##B = wpair(ROWPTR, g, 21, 20, S), \
     P##C = wpair(ROWPTR, g, 31, 30, S), P##D = wpair(ROWPTR, g, 29, 28, S), \
     P##E = wpair(ROWPTR, g, 24, 25, S), P##F = wpair(ROWPTR, g, 26, 27, S); \
  PIN(P##0);PIN(P##1);PIN(P##2);PIN(P##3);PIN(P##4);PIN(P##5);PIN(P##6);PIN(P##7); \
  PIN(P##8);PIN(P##9);PIN(P##A);PIN(P##B);PIN(P##C);PIN(P##D);PIN(P##E);PIN(P##F)

// dots: own-half slots (y0..y7) first, swizzled half (y8..yF) second,
// two accumulation chains; A0 seeded.
#define FDOT16(A0, A1, P, SEED) \
  float A0 = __builtin_amdgcn_fdot2(y0, P##0, (SEED), false); \
  float A1 = __builtin_amdgcn_fdot2(y1, P##1, 0.0f, false); \
  A0 = __builtin_amdgcn_fdot2(y2, P##2, A0, false);  A1 = __builtin_amdgcn_fdot2(y3, P##3, A1, false); \
  A0 = __builtin_amdgcn_fdot2(y4, P##4, A0, false);  A1 = __builtin_amdgcn_fdot2(y5, P##5, A1, false); \
  A0 = __builtin_amdgcn_fdot2(y6, P##6, A0, false);  A1 = __builtin_amdgcn_fdot2(y7, P##7, A1, false); \
  A0 = __builtin_amdgcn_fdot2(y8, P##8, A0, false);  A1 = __builtin_amdgcn_fdot2(y9, P##9, A1, false); \
  A0 = __builtin_amdgcn_fdot2(yA, P##A, A0, false);  A1 = __builtin_amdgcn_fdot2(yB, P##B, A1, false); \
  A0 = __builtin_amdgcn_fdot2(yC, P##C, A0, false);  A1 = __builtin_amdgcn_fdot2(yD, P##D, A1, false); \
  A0 = __builtin_amdgcn_fdot2(yE, P##E, A0, false);  A1 = __builtin_amdgcn_fdot2(yF, P##F, A1, false)

__global__ __launch_bounds__(256)
__attribute__((amdgpu_waves_per_eu(1, 1)))
void gru_bidir_head(const float* __restrict__ X,
                    const float* __restrict__ Wih_f, const float* __restrict__ Whh_f,
                    const float* __restrict__ bih_f, const float* __restrict__ bhh_f,
                    const float* __restrict__ Wih_b,
                    const float* __restrict__ bih_b, const float* __restrict__ bhh_b,
                    const float* __restrict__ W1, const float* __restrict__ b1,
                    const float* __restrict__ W2, const float* __restrict__ b2,
                    float* __restrict__ out)
{
  __shared__ float xbuf[8][TT];        // staged input rows (16 KB)
  __shared__ float obuf[8][64];        // [row][h_f(32) | h_b(32)] (2 KB)

  const int g  = threadIdx.x & 31;     // lane within row group = output index
  const int rs = threadIdx.x >> 5;     // row slot in block (0..7)
  const int b  = (blockIdx.x << 3) + rs;

  // --- stage this row of X into LDS (4 x vf4 per lane, coalesced) ---
  const vf4* Xr4 = (const vf4*)(X + (size_t)b * TT);
  vf4* xb4 = (vf4*)&xbuf[rs][0];
  #pragma unroll
  for (int q = 0; q < 4; ++q) xb4[g + 32 * q] = Xr4[g + 32 * q];
  __builtin_amdgcn_wave_barrier();

  // --- per-lane weights, pre-permuted to the gather slot order, f16 ---
  const float s1 = -LOG2E;             // r,z: sigmoid in exp2 domain
  const float s2 = 2.0f * LOG2E;       // n: tanh in exp2 domain
  const float* Wr_row = Whh_f + (size_t)(g)        * HH;
  const float* Wz_row = Whh_f + (size_t)(HH + g)   * HH;
  const float* Wn_row = Whh_f + (size_t)(2*HH + g) * HH;
  LDWG(Wr, Wr_row, s1);
  LDWG(Wz, Wz_row, s1);
  LDWG(Wn, Wn_row, s2);

  float xwr = Wih_f[g] * s1, xwz = Wih_f[HH + g] * s1, xwn = Wih_f[2*HH + g] * s2;
  float cbr = (bih_f[g]      + bhh_f[g])      * s1;
  float cbz = (bih_f[HH + g] + bhh_f[HH + g]) * s1;
  float cbn = bih_f[2*HH + g] * s2;            // n: b_ih term (with x)
  float cbh = bhh_f[2*HH + g] * s2;            // n: b_hh term (inside r*(...))
  PIN(xwr); PIN(xwz); PIN(xwn); PIN(cbr); PIN(cbz); PIN(cbn); PIN(cbh);

  float h = 0.0f;
  const vf4* xv = (const vf4*)&xbuf[rs][0];
  vf4 x4 = xv[0];

  #pragma unroll 1
  for (int tg = 0; tg < TT / 4; ++tg) {
    const vf4 x4n = xv[tg + 1 < TT / 4 ? tg + 1 : tg];   // off critical path

    float sr0 = __builtin_fmaf(x4.x, xwr, cbr), sz0 = __builtin_fmaf(x4.x, xwz, cbz),
          sn0 = __builtin_fmaf(x4.x, xwn, cbn);
    float sr1 = __builtin_fmaf(x4.y, xwr, cbr), sz1 = __builtin_fmaf(x4.y, xwz, cbz),
          sn1 = __builtin_fmaf(x4.y, xwn, cbn);
    float sr2 = __builtin_fmaf(x4.z, xwr, cbr), sz2 = __builtin_fmaf(x4.z, xwz, cbz),
          sn2 = __builtin_fmaf(x4.z, xwn, cbn);
    float sr3 = __builtin_fmaf(x4.w, xwr, cbr), sz3 = __builtin_fmaf(x4.w, xwz, cbz),
          sn3 = __builtin_fmaf(x4.w, xwn, cbn);

    #pragma unroll
    for (int u = 0; u < 4; ++u) {
      const float sr = (u == 0) ? sr0 : (u == 1) ? sr1 : (u == 2) ? sr2 : sr3;
      const float sz = (u == 0) ? sz0 : (u == 1) ? sz1 : (u == 2) ? sz2 : sz3;
      const float sn = (u == 0) ? sn0 : (u == 1) ? sn1 : (u == 2) ? sn2 : sn3;

      // ---- register all-gather of the 32 h values in this row group ----
      const f16 hf = (f16)h;
      const h2 self = {hf, hf};
      const int nb  = dpp<DPP_X1>(asI(self));            // h[g^1]
      const h2 pair = {self[0], asH2(nb)[0]};            // slot0: (0,1)
      const int p0 = asI(pair);
      const int p1 = dpp<DPP_X2>(p0);                    // (2,3)
      const int p2 = dpp<DPP_HM>(p0);                    // (7,6)
      const int p3 = dpp<DPP_HM>(p1);                    // (5,4)
      const int p4 = dpp<DPP_M>(p0);                     // (15,14)
      const int p5 = dpp<DPP_M>(p1);                     // (13,12)
      const int p6 = dpp<DPP_M>(p2);                     // (8,9)
      const int p7 = dpp<DPP_M>(p3);                     // (10,11)
      // other 16-half via crossbar (no memory, no barrier)
      const int q8 = __builtin_amdgcn_ds_swizzle(p0, SWZ_X16);
      const int q9 = __builtin_amdgcn_ds_swizzle(p1, SWZ_X16);
      const int qA = __builtin_amdgcn_ds_swizzle(p2, SWZ_X16);
      const int qB = __builtin_amdgcn_ds_swizzle(p3, SWZ_X16);
      const int qC = __builtin_amdgcn_ds_swizzle(p4, SWZ_X16);
      const int qD = __builtin_amdgcn_ds_swizzle(p5, SWZ_X16);
      const int qE = __builtin_amdgcn_ds_swizzle(p6, SWZ_X16);
      const int qF = __builtin_amdgcn_ds_swizzle(p7, SWZ_X16);

      const h2 y0 = asH2(p0), y1 = asH2(p1), y2 = asH2(p2), y3 = asH2(p3),
               y4 = asH2(p4), y5 = asH2(p5), y6 = asH2(p6), y7 = asH2(p7),
               y8 = asH2(q8), y9 = asH2(q9), yA = asH2(qA), yB = asH2(qB),
               yC = asH2(qC), yD = asH2(qD), yE = asH2(qE), yF = asH2(qF);

      FDOT16(Ra, Rb, Wr, sr);
      FDOT16(Za, Zb, Wz, sz);
      FDOT16(Na, Nb, Wn, cbh);

      const float ar = Ra + Rb;
      const float az = Za + Zb;
      const float r = __builtin_amdgcn_rcpf(1.0f + __builtin_amdgcn_exp2f(ar));
      const float z = __builtin_amdgcn_rcpf(1.0f + __builtin_amdgcn_exp2f(az));
      const float y = __builtin_fmaf(r, Na + Nb, sn);
      const float n = __builtin_fmaf(-2.0f,
          __builtin_amdgcn_rcpf(1.0f + __builtin_amdgcn_exp2f(y)), 1.0f);
      h = __builtin_fmaf(z, h - n, n);           // (1-z)*n + z*h
    }
    x4 = x4n;
  }

  // --- backward direction: exactly ONE GRU step from h0=0 on x[T-1] ---
  const float xl  = xbuf[rs][TT - 1];
  const float rb  = fast_sigm(__builtin_fmaf(xl, Wih_b[g],      bih_b[g]      + bhh_b[g]));
  const float zb  = fast_sigm(__builtin_fmaf(xl, Wih_b[HH + g], bih_b[HH + g] + bhh_b[HH + g]));
  const float xnb = __builtin_fmaf(xl, Wih_b[2*HH + g], bih_b[2*HH + g]);
  const float nb_ = fast_tanh(__builtin_fmaf(rb, bhh_b[2*HH + g], xnb));
  const float hb  = nb_ - zb * nb_;              // (1-zb)*nb + zb*0

  obuf[rs][g]      = h;                          // h_f (full fp32 state)
  obuf[rs][32 + g] = hb;                         // h_b
  __builtin_amdgcn_wave_barrier();

  // --- MLP head: sigmoid(W2 @ relu(W1 @ [h_f,h_b] + b1) + b2) ---
  const int j = g & 15;                          // lanes 16..31 duplicate
  const vf4* W1r = (const vf4*)(W1 + j * 64);
  const vf4* hc  = (const vf4*)&obuf[rs][0];
  vf4 a4 = W1r[0] * hc[0];
  #pragma unroll
  for (int q = 1; q < 16; ++q)
    a4 = __builtin_elementwise_fma(W1r[q], hc[q], a4);
  float acc = b1[j] + (a4.x + a4.y) + (a4.z + a4.w);
  float h1 = fmaxf(acc, 0.0f) * W2[j];
  h1 += __shfl_down(h1, 8, 16);
  h1 += __shfl_down(h1, 4, 16);
  h1 += __shfl_down(h1, 2, 16);
  h1 += __shfl_down(h1, 1, 16);
  if (g == 0) out[b] = fast_sigm(h1 + b2[0]);
}

extern "C" void kernel_launch(void* const* d_in, const int* in_sizes, int n_in,
                              void* d_out, int out_size, void* d_ws, size_t ws_size,
                              hipStream_t stream) {
  const float* X     = (const float*)d_in[0];
  const float* Wih_f = (const float*)d_in[1];
  const float* Whh_f = (const float*)d_in[2];
  const float* bih_f = (const float*)d_in[3];
  const float* bhh_f = (const float*)d_in[4];
  const float* Wih_b = (const float*)d_in[5];
  // d_in[6] = W_hh_b: unused — backward direction runs exactly one step from h0=0.
  const float* bih_b = (const float*)d_in[7];
  const float* bhh_b = (const float*)d_in[8];
  const float* W1    = (const float*)d_in[9];
  const float* b1    = (const float*)d_in[10];
  const float* W2    = (const float*)d_in[11];
  const float* b2    = (const float*)d_in[12];
  float* out = (float*)d_out;

  // 2048 rows / 8 rows per 256-thread block = 256 blocks = 1 block/CU,
  // 1024 waves = 1 wave/SIMD (2 rows per wave as half-waves).
  gru_bidir_head<<<256, 256, 0, stream>>>(X, Wih_f, Whh_f, bih_f, bhh_f,
                                          Wih_b, bih_b, bhh_b, W1, b1, W2, b2, out);
}